// Round 9
// baseline (40.929 us; speedup 1.0000x reference)
//
#include <hip/hip_runtime.h>

typedef __attribute__((ext_vector_type(8))) short short8;
typedef __attribute__((ext_vector_type(16))) float f32x16;

#define NROWS_IN 1600
#define NI 5000
#define BB 32
#define DDk 4
#define SS 50
#define NTILES 79

__device__ __forceinline__ unsigned short f2bf(float f) {
    unsigned int u = __float_as_uint(f);
    u = (u + 0x7FFFu + ((u >> 16) & 1u)) >> 16;   // RNE
    return (unsigned short)u;
}
__device__ __forceinline__ float b2f(unsigned short u) {
    return __uint_as_float(((unsigned int)u) << 16);
}

// ---------------------------------------------------------------------------
// k_prep: blk 0..15   : Wd (512x128 f32) -> Wcat[0..512) bf16
//         blk 16..79  : Wcomb[d*128+o][e] = sum_h Wk[o][h]*Wd[d*128+h][e]
//         blk 80..904 : gather emb rows -> fp32 outs + bf16 Abf
// (byte-identical to round 8)
// ---------------------------------------------------------------------------
__global__ __launch_bounds__(256) void k_prep(const int* __restrict__ inp,
                                              const int* __restrict__ cand,
                                              const float* __restrict__ et,
                                              const float* __restrict__ Wd,
                                              const float* __restrict__ Ws,
                                              unsigned short* __restrict__ Wcat,
                                              unsigned short* __restrict__ Abf,
                                              float* __restrict__ o_emb,
                                              float* __restrict__ o_cemb) {
    int t = threadIdx.x;
    int blk = blockIdx.x;
    if (blk < 16) {
        const float4* src = (const float4*)Wd;
#pragma unroll
        for (int q = 0; q < 4; ++q) {
            int i = blk * 256 + t + q * 4096;   // 0..16383 float4s
            float4 v = src[i];
            ushort4 o;
            o.x = f2bf(v.x); o.y = f2bf(v.y); o.z = f2bf(v.z); o.w = f2bf(v.w);
            *(ushort4*)(Wcat + (size_t)i * 4) = o;
        }
        return;
    }
    if (blk < 80) {
        __shared__ __align__(16) float sdw[128 * 128];   // Wd_d tile [h][e]
        __shared__ float wk[8][128];
        int cb = blk - 16;                    // 0..63
        int d = cb >> 4, ot = cb & 15;
        const float4* src = (const float4*)(Wd + (size_t)d * 128 * 128);
#pragma unroll
        for (int q = 0; q < 16; ++q) {
            int i = t + q * 256;              // 4096 float4s
            *(float4*)(&sdw[i * 4]) = src[i];
        }
        for (int x = t; x < 8 * 128; x += 256) {
            int ol = x >> 7, h = x & 127;
            wk[ol][h] = Ws[(ot * 8 + ol) * 256 + 128 + h];
        }
        __syncthreads();
        int e = t & 127, og = t >> 7;
        float acc[4] = {0.f, 0.f, 0.f, 0.f};
        for (int h = 0; h < 128; ++h) {
            float rd = sdw[h * 128 + e];
#pragma unroll
            for (int k = 0; k < 4; ++k) acc[k] += rd * wk[og * 4 + k][h];
        }
#pragma unroll
        for (int k = 0; k < 4; ++k) {
            int o = ot * 8 + og * 4 + k;
            Wcat[(size_t)(512 + d * 128 + o) * 128 + e] = f2bf(acc[k]);
        }
        return;
    }
    // pregather: 825 blocks x 8 rows
    int pb = blk - 80;
    int r = pb * 8 + (t >> 5);                // 0..6599
    int fc = t & 31;
    int id = (r < NROWS_IN) ? inp[r] : cand[r - NROWS_IN];
    float4 v = *(const float4*)(et + (size_t)id * 128 + fc * 4);
    if (r < NROWS_IN) *(float4*)(o_emb + (size_t)r * 128 + fc * 4) = v;
    else              *(float4*)(o_cemb + (size_t)(r - NROWS_IN) * 128 + fc * 4) = v;
    ushort4 o;
    o.x = f2bf(v.x); o.y = f2bf(v.y); o.z = f2bf(v.z); o.w = f2bf(v.w);
    *(ushort4*)(Abf + (size_t)r * 128 + fc * 4) = o;
}

// ---------------------------------------------------------------------------
// k_fused_mid: one block per (b,d), 128 blocks x 512 threads (8 waves).
// Each wave owns one 32x32 acc (rt = row group, ct = 32-col group); 2
// waves/SIMD hide latency within each barrier phase. A fragments in regs,
// reused by both MFMAs.
// ---------------------------------------------------------------------------
__global__ __launch_bounds__(512) void k_fused_mid(const unsigned short* __restrict__ Abf,
                                                   const unsigned short* __restrict__ Wcat,
                                                   const float* __restrict__ Ws,
                                                   const float* __restrict__ bsc,
                                                   const float* __restrict__ wsc,
                                                   float* __restrict__ aggw,
                                                   float* __restrict__ apw,
                                                   float* __restrict__ o_ds) {
    __shared__ __align__(16) char lds[37152];
    unsigned short* sb   = (unsigned short*)lds;             // 128x128 bf16 (32K)
    float*          skp  = (float*)lds;                      // 64x128 f32 (overlay)
    float*          sred = (float*)(lds + 32768);            // 128x5
    float*          sagg = (float*)(lds + 35328);            // 128
    float*          sap  = (float*)(lds + 35840);            // 128
    float*          spart= (float*)(lds + 36352);            // 200

    int b = blockIdx.x >> 2, d = blockIdx.x & 3;
    int t = threadIdx.x;
    int w = t >> 6, lane = t & 63;
    int lr = lane & 31, g = lane >> 5;
    int rt = w & 1, ct = w >> 1;          // ct 0..3 (32-col groups)
    int arow = rt * 32 + lr;

    // A fragments direct to registers (rows b*50+arow; zero beyond SS)
    short8 a8[8];
    {
        const unsigned short* arp = Abf + (size_t)(b * SS + arow) * 128;
#pragma unroll
        for (int ks = 0; ks < 8; ++ks) {
            short8 v = {0, 0, 0, 0, 0, 0, 0, 0};
            if (arow < SS) v = *(const short8*)(arp + (ks * 2 + g) * 8);
            a8[ks] = v;
        }
    }
    // stage sb: Wd_d = Wcat rows d*128..+128  (2048 chunks / 512 threads)
#pragma unroll
    for (int q = 0; q < 4; ++q) {
        int x = t + q * 512;
        int r = x >> 4, ch = x & 15;
        short8 v = *(const short8*)(Wcat + (size_t)(d * 128 + r) * 128 + ch * 8);
        *(short8*)(sb + r * 128 + ((ch ^ (r & 15)) << 3)) = v;
    }
    __syncthreads();

    int bcol = ct * 32 + lr;               // 0..127
    const unsigned short* pb = sb + bcol * 128;
    int bx = bcol & 15;
    // MFMA1: hidden (one 32x32 acc per wave)
    f32x16 h0 = {};
#pragma unroll
    for (int ks = 0; ks < 8; ++ks) {
        int chA = ks * 2 + g;
        short8 b8 = *(const short8*)(pb + ((chA ^ bx) << 3));
        h0 = __builtin_amdgcn_mfma_f32_32x32x16_bf16(a8[ks], b8, h0, 0, 0, 0);
    }
    // exp partial over valid rows
    float p0 = 0.f;
#pragma unroll
    for (int r = 0; r < 16; ++r) {
        int row = rt * 32 + (r & 3) + 8 * (r >> 2) + 4 * g;
        if (row < SS) p0 += expf(h0[r]);
    }
    sred[bcol * 5 + rt * 2 + g] = p0;
    __syncthreads();
    // restage sb <- Wcomb_d; agg concurrently
#pragma unroll
    for (int q = 0; q < 4; ++q) {
        int x = t + q * 512;
        int r = x >> 4, ch = x & 15;
        short8 v = *(const short8*)(Wcat + (size_t)(512 + d * 128 + r) * 128 + ch * 8);
        *(short8*)(sb + r * 128 + ((ch ^ (r & 15)) << 3)) = v;
    }
    if (t < 128) {
        float s = sred[t * 5] + sred[t * 5 + 1] + sred[t * 5 + 2] + sred[t * 5 + 3];
        float a = logf(s);
        sagg[t] = a;
        aggw[b * 512 + d * 128 + t] = a;
    }
    __syncthreads();
    // MFMA2: kp (reuses a8)
    f32x16 k0 = {};
#pragma unroll
    for (int ks = 0; ks < 8; ++ks) {
        int chA = ks * 2 + g;
        short8 b8 = *(const short8*)(pb + ((chA ^ bx) << 3));
        k0 = __builtin_amdgcn_mfma_f32_32x32x16_bf16(a8[ks], b8, k0, 0, 0, 0);
    }
    // ap
    if (t < 128) {
        const float* wr = Ws + t * 256;
        float acc = bsc[t];
        for (int ch = 0; ch < 32; ++ch) {
            float4 a4 = *(const float4*)(sagg + ch * 4);
            float4 w4 = *(const float4*)(wr + ch * 4);
            acc += a4.x * w4.x + a4.y * w4.y + a4.z * w4.z + a4.w * w4.w;
        }
        sap[t] = acc;
        apw[(b * DDk + d) * 128 + t] = acc;
    }
    __syncthreads();   // all waves done reading sb; sap ready
    // scatter kp -> skp (swizzled f32, overlays sb)
#pragma unroll
    for (int r = 0; r < 16; ++r) {
        int row = rt * 32 + (r & 3) + 8 * (r >> 2) + 4 * g;
        int c0 = ct * 32 + lr;
        skp[row * 128 + ((((c0 >> 2) ^ (row & 7)) << 2) | (c0 & 3))] = k0[r];
    }
    __syncthreads();
    // score: thread (s = t>>2, oq = t&3) -> 32-o partial
    if (t < 200) {
        int s = t >> 2, oq = t & 3;
        float acc = 0.f;
#pragma unroll
        for (int c = 0; c < 8; ++c) {
            int ch = oq * 8 + c;
            float4 a4 = *(const float4*)(sap + ch * 4);
            float4 w4 = *(const float4*)(wsc + ch * 4);
            float4 k4 = *(const float4*)(&skp[s * 128 + ((ch ^ (s & 7)) << 2)]);
            acc += w4.x * fmaxf(a4.x + k4.x, 0.f) + w4.y * fmaxf(a4.y + k4.y, 0.f)
                 + w4.z * fmaxf(a4.z + k4.z, 0.f) + w4.w * fmaxf(a4.w + k4.w, 0.f);
        }
        spart[t] = acc;
    }
    __syncthreads();
    if (t < SS) {
        float v = spart[t * 4] + spart[t * 4 + 1] + spart[t * 4 + 2] + spart[t * 4 + 3];
        o_ds[b * (DDk * SS) + d * SS + t] = v;
    }
}

// ---------------------------------------------------------------------------
// k_cand: blocks 0..1263: (64-i tile, d, b-group of 8). Each block computes
// the 64x128 cp tile by MFMA (A in regs), scatters f32 to LDS, scores its
// 8 b's x 64 i's. 37.4 KB LDS -> 4 blocks/CU; grid ~4.9 blocks/CU.
// block 1264: demand_sim_loss.
// ---------------------------------------------------------------------------
__global__ __launch_bounds__(256) void k_cand(const unsigned short* __restrict__ Abf,
                                              const unsigned short* __restrict__ Wcat,
                                              const float* __restrict__ apw,
                                              const float* __restrict__ aggw,
                                              const float* __restrict__ wsc,
                                              float* __restrict__ o_dsc,
                                              float* __restrict__ o_loss) {
    __shared__ __align__(16) char lds[37376];
    int gid = blockIdx.x;
    int t = threadIdx.x;
    if (gid >= NTILES * 16) {               // ---- loss block ----
        float* nrm = (float*)lds;           // 128 floats
        if (t < 128) {
            const float* a = aggw + t * 128;
            float s = 0.f;
            for (int h = 0; h < 128; ++h) s += a[h] * a[h];
            nrm[t] = fmaxf(sqrtf(s), 1e-8f);
        }
        __syncthreads();
        float lb = 0.f;
        if (t < 32) {
            const float* a = aggw + t * 512;
            float i0 = 1.f / nrm[t * 4 + 0], i1 = 1.f / nrm[t * 4 + 1];
            float i2 = 1.f / nrm[t * 4 + 2], i3 = 1.f / nrm[t * 4 + 3];
            for (int h = 0; h < 128; ++h) {
                float u0 = a[h] * i0, u1 = a[128 + h] * i1;
                float u2 = a[256 + h] * i2, u3 = a[384 + h] * i3;
                float v = u0 + u1 + u2 + u3;
                lb += v * v - (u0 * u0 + u1 * u1 + u2 * u2 + u3 * u3);
            }
        }
        for (int off = 32; off; off >>= 1) lb += __shfl_down(lb, off);
        if (t == 0) o_loss[0] = lb / (float)(BB * DDk * (DDk - 1));
        return;
    }
    unsigned short* sw  = (unsigned short*)lds;              // 128x128 bf16 (32K)
    float*          scp = (float*)lds;                       // 64x128 f32 (overlay)
    float*          sap = (float*)(lds + 32768);             // 8x128 f32 (4K)
    float*          swv = (float*)(lds + 36864);             // 128 f32

    int tile = gid >> 4;
    int sub = gid & 15;
    int d = sub >> 2, bg = sub & 3;
    int i0 = tile * 64;
    int w = t >> 6, lane = t & 63;
    int rbase = (w & 1) * 32, cbase = (w >> 1) * 64;
    int lr = lane & 31, g = lane >> 5;
    int arow = rbase + lr;

    // A fragments (cand rows i0+arow)
    short8 a8[8];
    {
        const unsigned short* arp = Abf + (size_t)(NROWS_IN + i0 + arow) * 128;
        bool valid = (i0 + arow < NI);
#pragma unroll
        for (int ks = 0; ks < 8; ++ks) {
            short8 v = {0, 0, 0, 0, 0, 0, 0, 0};
            if (valid) v = *(const short8*)(arp + (ks * 2 + g) * 8);
            a8[ks] = v;
        }
    }
    // stage sw: Wcomb_d
#pragma unroll
    for (int q = 0; q < 8; ++q) {
        int x = t + q * 256;
        int r = x >> 4, ch = x & 15;
        short8 v = *(const short8*)(Wcat + (size_t)(512 + d * 128 + r) * 128 + ch * 8);
        *(short8*)(sw + r * 128 + ((ch ^ (r & 15)) << 3)) = v;
    }
    // stage sap (8 b rows of this bg) + swv
    if (t < 128) swv[t] = wsc[t];
    {
        int bi = t >> 5, ch = t & 31;       // 256 float4s exactly
        float4 v = *(const float4*)(apw + (size_t)((bg * 8 + bi) * 4 + d) * 128 + ch * 4);
        *(float4*)(&sap[bi * 128 + ((ch ^ (bi & 7)) << 2)]) = v;
    }
    __syncthreads();
    // GEMM: 64x128 cp tile
    int bcol0 = cbase + lr, bcol1 = cbase + 32 + lr;
    const unsigned short* pb0 = sw + bcol0 * 128;
    const unsigned short* pb1 = sw + bcol1 * 128;
    int b0x = bcol0 & 15, b1x = bcol1 & 15;
    f32x16 acc0 = {}, acc1 = {};
#pragma unroll
    for (int ks = 0; ks < 8; ++ks) {
        int chA = ks * 2 + g;
        short8 b8 = *(const short8*)(pb0 + ((chA ^ b0x) << 3));
        short8 c8 = *(const short8*)(pb1 + ((chA ^ b1x) << 3));
        acc0 = __builtin_amdgcn_mfma_f32_32x32x16_bf16(a8[ks], b8, acc0, 0, 0, 0);
        acc1 = __builtin_amdgcn_mfma_f32_32x32x16_bf16(a8[ks], c8, acc1, 0, 0, 0);
    }
    __syncthreads();                        // done reading sw
    // scatter cp tile into scp (f32, il&31 swizzle)
#pragma unroll
    for (int r = 0; r < 16; ++r) {
        int row = rbase + (r & 3) + 8 * (r >> 2) + 4 * g;
        int c0 = cbase + lr, c1 = cbase + 32 + lr;
        scp[row * 128 + ((((c0 >> 2) ^ (row & 31)) << 2) | (c0 & 3))] = acc0[r];
        scp[row * 128 + ((((c1 >> 2) ^ (row & 31)) << 2) | (c1 & 3))] = acc1[r];
    }
    __syncthreads();
    // score: thread (bo = t>>5 in [0,8), gg = t&31) -> i = i0+gg, i0+32+gg
    int bo = t >> 5, gg = t & 31;
    float accA = 0.f, accB = 0.f;
    const float* sapA = sap + bo * 128;
    for (int ch = 0; ch < 32; ++ch) {
        float4 w4 = *(const float4*)(swv + ch * 4);
        float4 a4 = *(const float4*)(sapA + ((ch ^ bo) << 2));
        float4 cA = *(const float4*)(&scp[gg * 128 + ((ch ^ gg) << 2)]);
        float4 cB = *(const float4*)(&scp[(32 + gg) * 128 + ((ch ^ gg) << 2)]);
        accA += w4.x * fmaxf(a4.x + cA.x, 0.f) + w4.y * fmaxf(a4.y + cA.y, 0.f)
              + w4.z * fmaxf(a4.z + cA.z, 0.f) + w4.w * fmaxf(a4.w + cA.w, 0.f);
        accB += w4.x * fmaxf(a4.x + cB.x, 0.f) + w4.y * fmaxf(a4.y + cB.y, 0.f)
              + w4.z * fmaxf(a4.z + cB.z, 0.f) + w4.w * fmaxf(a4.w + cB.w, 0.f);
    }
    {
        size_t base = (size_t)(bg * 8 + bo) * (DDk * NI) + d * NI;
        int ia = i0 + gg;
        if (ia < NI)      o_dsc[base + ia]      = accA;
        if (ia + 32 < NI) o_dsc[base + ia + 32] = accB;
    }
}

// ---------------------------------------------------------------------------
extern "C" void kernel_launch(void* const* d_in, const int* in_sizes, int n_in,
                              void* d_out, int out_size, void* d_ws, size_t ws_size,
                              hipStream_t stream) {
    const int*   inp  = (const int*)d_in[0];
    const int*   cand = (const int*)d_in[1];
    const float* et   = (const float*)d_in[2];
    const float* Wd   = (const float*)d_in[3];
    const float* Ws   = (const float*)d_in[4];
    const float* bsc  = (const float*)d_in[5];
    const float* wsc  = (const float*)d_in[6];

    float* out = (float*)d_out;
    float* o_ds   = out;                  // (B,D,S)    6400
    float* o_dsc  = out + 6400;           // (B,D,I)    640000
    float* o_emb  = out + 646400;         // (B,S,E)    204800
    float* o_cemb = out + 851200;         // (I,E)      640000
    float* o_loss = out + 1491200;        // scalar

    char* wsb = (char*)d_ws;
    unsigned short* Wcat = (unsigned short*)wsb;              // 1024x128 bf16
    unsigned short* Abf  = (unsigned short*)(wsb + 262144);   // 6600x128 bf16
    float* aggw = (float*)(wsb + 2097152);                    // 16384 f32
    float* apw  = aggw + 16384;                               // 16384 f32

    hipLaunchKernelGGL(k_prep, dim3(905), dim3(256), 0, stream,
                       inp, cand, et, Wd, Ws, Wcat, Abf, o_emb, o_cemb);
    hipLaunchKernelGGL(k_fused_mid, dim3(128), dim3(512), 0, stream,
                       Abf, Wcat, Ws, bsc, wsc, aggw, apw, o_ds);
    hipLaunchKernelGGL(k_cand, dim3(NTILES * 16 + 1), dim3(256), 0, stream,
                       Abf, Wcat, apw, aggw, wsc, o_dsc, o_loss);
}